// Round 13
// baseline (159.748 us; speedup 1.0000x reference)
//
#include <hip/hip_runtime.h>
#include <hip/hip_fp16.h>

// SIREN, single fused kernel, register-resident, 128 points/wave.
// R13: HYBRID SINE — half the sins on the transcendental pipe (v_sin_f32),
// half as a deg-9 fp32 polynomial on the full-rate FMA pipe, interleaved
// element-wise so both execution pipes are fed concurrently. The R6..R12
// invariant (dur ~59us, VALUBusy*dur ~40us regardless of MFMA/occupancy/LDS
// changes) identifies the trans pipe as the wall; this splits its load.
// Poly: endpoint-corrected Taylor for sin(2*pi*r), r in [-1/2,1/2] (P(+-1/2)=0
// preserves wrap continuity); max err ~5e-4 on half the elements.
// Everything else = R12: sigma-permuted in-register MFMA pipeline, hi-f16
// weights, no LDS, no workspace, single kernel.

#define SINSCALE 4.774648292756860f   // 30/(2*pi)

typedef __attribute__((ext_vector_type(8))) _Float16 half8;
typedef __attribute__((ext_vector_type(2))) __fp16 fp16x2;
typedef __attribute__((ext_vector_type(4))) float f32x4;

union S16 { uint4 u4; half8 h; };
union PK { fp16x2 h2; unsigned int u; };

__device__ __forceinline__ float fast_sigmoid(float t) {
    float e = __builtin_amdgcn_exp2f(t * -1.4426950408889634f);
    return 1.0f / (1.0f + e);
}

__device__ __forceinline__ unsigned int pk2(float a, float b) {
    PK p; p.h2 = __builtin_amdgcn_cvt_pkrtz(a, b);
    return p.u;
}

// trans-pipe sine (revolutions)
__device__ __forceinline__ float tsin(float c) {
    return __builtin_amdgcn_sinf(c);
}

// VALU polynomial sine (revolutions): sin(2*pi*c), deg-9 odd, endpoint-corrected.
__device__ __forceinline__ float psin(float c) {
    float r = c - __builtin_rintf(c);          // v_rndne + v_sub, r in [-0.5,0.5]
    float t = r * r;
    float p = fmaf(t, 38.5130f, -76.705859f);  // c9 (corrected), c7
    p = fmaf(t, p, 81.605249f);                // c5
    p = fmaf(t, p, -41.341702f);               // c3
    p = fmaf(t, p, 6.2831853f);                // c1
    return p * r;
}

// Build the sigma-permuted A-fragment (hi f16, RTZ) for feature rows m:
// slots j=0..3 <- W[m][4q+j]*S, j=4..7 <- W[m][16+4q+(j-4)]*S.
__device__ __forceinline__ uint4 build_frag(const float* __restrict__ W, int m, int q) {
    const float4 fa = *reinterpret_cast<const float4*>(&W[m * 32 + 4 * q]);
    const float4 fb = *reinterpret_cast<const float4*>(&W[m * 32 + 16 + 4 * q]);
    uint4 u;
    u.x = pk2(fa.x * SINSCALE, fa.y * SINSCALE);
    u.y = pk2(fa.z * SINSCALE, fa.w * SINSCALE);
    u.z = pk2(fb.x * SINSCALE, fb.y * SINSCALE);
    u.w = pk2(fb.z * SINSCALE, fb.w * SINSCALE);
    return u;
}

// Scaled bias vector for C/D rows 4q..4q+3 (+off)
__device__ __forceinline__ f32x4 bias_frag(const float* __restrict__ b, int off, int q) {
    const float4 t = *reinterpret_cast<const float4*>(&b[off + 4 * q]);
    f32x4 r = {t.x * SINSCALE, t.y * SINSCALE, t.z * SINSCALE, t.w * SINSCALE};
    return r;
}

__global__ __launch_bounds__(256, 4) void siren_mfma(
    const float* __restrict__ coords,
    const float* __restrict__ w0, const float* __restrict__ b0,
    const float* __restrict__ w1, const float* __restrict__ b1,
    const float* __restrict__ w2, const float* __restrict__ b2,
    const float* __restrict__ w3, const float* __restrict__ b3,
    const float* __restrict__ w4, const float* __restrict__ b4,
    const float* __restrict__ w5, const float* __restrict__ b5,
    const float* __restrict__ wf, const float* __restrict__ bfin,
    float* __restrict__ out, int n) {
    const int lane = (int)(threadIdx.x & 63);
    const int q = lane >> 4;
    const int nl = lane & 15;
    const int pbase = blockIdx.x * 512 + (int)(threadIdx.x >> 6) * 128;

    // ---- weight fragments for layers 1..5, built from raw matrices ----
    uint4 Af[4][2];
    Af[0][0] = build_frag(w1, nl, q);  Af[0][1] = build_frag(w1, 16 + nl, q);
    Af[1][0] = build_frag(w2, nl, q);  Af[1][1] = build_frag(w2, 16 + nl, q);
    Af[2][0] = build_frag(w3, nl, q);  Af[2][1] = build_frag(w3, 16 + nl, q);
    Af[3][0] = build_frag(w4, nl, q);  Af[3][1] = build_frag(w4, 16 + nl, q);
    const uint4 Af5 = build_frag(w5, nl, q);

    // ---- L0: 2 -> 32 directly in B-frag format (features sigma(8q+j)) ----
    const float4 wa = *reinterpret_cast<const float4*>(&w0[8 * q]);
    const float4 wb = *reinterpret_cast<const float4*>(&w0[8 * q + 4]);
    const float4 wc = *reinterpret_cast<const float4*>(&w0[32 + 8 * q]);
    const float4 wd = *reinterpret_cast<const float4*>(&w0[32 + 8 * q + 4]);
    const float4 ba = *reinterpret_cast<const float4*>(&b0[4 * q]);
    const float4 bc = *reinterpret_cast<const float4*>(&b0[16 + 4 * q]);
    float wxs[8] = {wa.x, wa.z, wb.x, wb.z, wc.x, wc.z, wd.x, wd.z};
    float wys[8] = {wa.y, wa.w, wb.y, wb.w, wc.y, wc.w, wd.y, wd.w};
    float bbs[8] = {ba.x, ba.y, ba.z, ba.w, bc.x, bc.y, bc.z, bc.w};
#pragma unroll
    for (int j = 0; j < 8; ++j) {
        wxs[j] *= SINSCALE;
        wys[j] *= SINSCALE;
        bbs[j] *= SINSCALE;
    }

    uint4 Bt[8];
#pragma unroll
    for (int t = 0; t < 8; ++t) {
        int ptc = min(pbase + 16 * t + nl, n - 1);
        float2 c = reinterpret_cast<const float2*>(coords)[ptc];
        float s[8];
#pragma unroll
        for (int j = 0; j < 8; ++j) {
            float a = fmaf(wxs[j], c.x, fmaf(wys[j], c.y, bbs[j]));
            s[j] = (j & 1) ? psin(a) : tsin(a);
        }
        Bt[t].x = pk2(s[0], s[1]);
        Bt[t].y = pk2(s[2], s[3]);
        Bt[t].z = pk2(s[4], s[5]);
        Bt[t].w = pk2(s[6], s[7]);
    }

    // ---- middle layers 1..4 (fully unrolled), hi-weights only ----
    const float* Bs[4] = {b1, b2, b3, b4};
#pragma unroll
    for (int l = 0; l < 4; ++l) {
        S16 Ah0, Ah1;
        Ah0.u4 = Af[l][0];
        Ah1.u4 = Af[l][1];
        const f32x4 bv0 = bias_frag(Bs[l], 0, q);
        const f32x4 bv1 = bias_frag(Bs[l], 16, q);
#pragma unroll
        for (int t = 0; t < 8; ++t) {
            S16 B;
            B.u4 = Bt[t];
            f32x4 c0 = __builtin_amdgcn_mfma_f32_16x16x32_f16(Ah0.h, B.h, bv0, 0, 0, 0);
            f32x4 c1 = __builtin_amdgcn_mfma_f32_16x16x32_f16(Ah1.h, B.h, bv1, 0, 0, 0);
            Bt[t].x = pk2(tsin(c0[0]), psin(c0[1]));
            Bt[t].y = pk2(tsin(c0[2]), psin(c0[3]));
            Bt[t].z = pk2(tsin(c1[0]), psin(c1[1]));
            Bt[t].w = pk2(tsin(c1[2]), psin(c1[3]));
        }
    }

    // ---- L5 (32->16) + final (16->3): registers + shfl butterfly ----
    {
        S16 Ah5;
        Ah5.u4 = Af5;
        const f32x4 bv5 = bias_frag(b5, 0, q);
        float4 wfl[3];
#pragma unroll
        for (int c = 0; c < 3; ++c)
            wfl[c] = *reinterpret_cast<const float4*>(&wf[c * 16 + 4 * q]);

        float red[8][3];
#pragma unroll
        for (int t = 0; t < 8; ++t) {
            S16 B;
            B.u4 = Bt[t];
            f32x4 c5 = __builtin_amdgcn_mfma_f32_16x16x32_f16(Ah5.h, B.h, bv5, 0, 0, 0);
            float h0 = tsin(c5[0]);
            float h1 = psin(c5[1]);
            float h2 = tsin(c5[2]);
            float h3 = psin(c5[3]);
#pragma unroll
            for (int c = 0; c < 3; ++c)
                red[t][c] = fmaf(wfl[c].x, h0, fmaf(wfl[c].y, h1,
                            fmaf(wfl[c].z, h2, wfl[c].w * h3)));
        }
        // butterfly over the 4 q-lanes sharing a point column
#pragma unroll
        for (int t = 0; t < 8; ++t)
#pragma unroll
            for (int c = 0; c < 3; ++c) {
                float v = red[t][c];
                v += __shfl_xor(v, 16, 64);
                v += __shfl_xor(v, 32, 64);
                red[t][c] = v;
            }
        // lane outputs two points: t=q (pts 0..63) and t=4+q (pts 64..127)
        float o0[3], o1[3];
#pragma unroll
        for (int c = 0; c < 3; ++c) {
            float v01 = (q & 1) ? red[1][c] : red[0][c];
            float v23 = (q & 1) ? red[3][c] : red[2][c];
            o0[c] = fast_sigmoid(((q & 2) ? v23 : v01) + bfin[c]);
            float w01 = (q & 1) ? red[5][c] : red[4][c];
            float w23 = (q & 1) ? red[7][c] : red[6][c];
            o1[c] = fast_sigmoid(((q & 2) ? w23 : w01) + bfin[c]);
        }
        const int p0 = pbase + 16 * q + nl;
        const int p1 = p0 + 64;
        if (p0 < n) {
            out[3 * p0 + 0] = o0[0];
            out[3 * p0 + 1] = o0[1];
            out[3 * p0 + 2] = o0[2];
        }
        if (p1 < n) {
            out[3 * p1 + 0] = o1[0];
            out[3 * p1 + 1] = o1[1];
            out[3 * p1 + 2] = o1[2];
        }
    }
}

extern "C" void kernel_launch(void* const* d_in, const int* in_sizes, int n_in,
                              void* d_out, int out_size, void* d_ws, size_t ws_size,
                              hipStream_t stream) {
    const float* coords = (const float*)d_in[0];
    const float* w0 = (const float*)d_in[1];
    const float* b0 = (const float*)d_in[2];
    const float* w1 = (const float*)d_in[3];
    const float* b1 = (const float*)d_in[4];
    const float* w2 = (const float*)d_in[5];
    const float* b2 = (const float*)d_in[6];
    const float* w3 = (const float*)d_in[7];
    const float* b3 = (const float*)d_in[8];
    const float* w4 = (const float*)d_in[9];
    const float* b4 = (const float*)d_in[10];
    const float* w5 = (const float*)d_in[11];
    const float* b5 = (const float*)d_in[12];
    const float* wf = (const float*)d_in[13];
    const float* bf = (const float*)d_in[14];
    float* out = (float*)d_out;

    const int n = in_sizes[0] / 2;

    siren_mfma<<<(n + 511) / 512, 256, 0, stream>>>(
        coords, w0, b0, w1, b1, w2, b2, w3, b3, w4, b4, w5, b5, wf, bf, out, n);
}